// Round 7
// baseline (1027.397 us; speedup 1.0000x reference)
//
#include <hip/hip_runtime.h>
#include <math.h>

// ---------------------------------------------------------------------------
// MPNNPropPred, R7: single persistent kernel with SOFTWARE grid barrier
// (cooperative launch was rejected in R6 -> output never written).
// 512 blocks x 256 thr; LDS 62.5KB -> 2 blocks/CU capacity; launch_bounds
// (256,2) caps VGPR<=256 -> 8 waves/CU fits -> all 512 blocks co-resident
// by construction, so the barrier spin cannot deadlock.
// N=20000, E=50000, B=128, H=64. All f32.
// ---------------------------------------------------------------------------

#define NN 20000
#define NE 50000
#define NB 128
#define HD 64
#define NFEAT 28
#define NTYPES 100
#define EDIM 5
#define S2SIT 4
#define NBLK 196                  // ceil(NE/256)
#define NSB 79                    // ceil(NN/256)
#define SMAX 224
#define HP (HD + 1)
#define GRID 512
#define NWAVE (GRID * 4)

struct S2SM {
  float hs[SMAX * HP];
  float ebuf[SMAX];
  float qstar[2 * HD];
  float hxs[HD], cxs[HD], gates[4 * HD];
  float redM[4], redS[4], redR[4][HD];
  float hid[HD];
};
union SharedU {
  S2SM s;
  int scanbuf[256];
  int wc[4][EDIM];
  float emv[HD];
};

__device__ __forceinline__ float sigm(float x) {
  return 1.0f / (1.0f + expf(-x));
}

// software grid barrier: bar[0]=cumulative arrivals, bar[1]=completed phases.
// Cumulative counter -> no reset race. Agent-scope atomics + threadfence
// (release: L2 writeback; acquire: L1/L2 inv) for cross-XCD visibility.
__device__ __forceinline__ void gsync(int* bar, int phase) {
  __syncthreads();
  if (threadIdx.x == 0) {
    __threadfence();
    int prev = __hip_atomic_fetch_add(&bar[0], 1, __ATOMIC_ACQ_REL,
                                      __HIP_MEMORY_SCOPE_AGENT);
    if (prev + 1 == GRID * (phase + 1)) {
      __hip_atomic_store(&bar[1], phase + 1, __ATOMIC_RELEASE,
                         __HIP_MEMORY_SCOPE_AGENT);
    } else {
      while (__hip_atomic_load(&bar[1], __ATOMIC_ACQUIRE,
                               __HIP_MEMORY_SCOPE_AGENT) < phase + 1)
        __builtin_amdgcn_s_sleep(2);
    }
    __threadfence();
  }
  __syncthreads();
}

// root: hnext[n][o] = bias[o] + sum_k h[n][k]*root[k][o] (inits hnext)
__device__ __forceinline__ void root_phase(const float* __restrict__ h,
    float* __restrict__ hnext, const float* __restrict__ root,
    const float* __restrict__ bias, int lane) {
  int wid = __builtin_amdgcn_readfirstlane(blockIdx.x * 4 + (threadIdx.x >> 6));
  float w[HD];
  #pragma unroll
  for (int k = 0; k < HD; ++k) w[k] = root[k * HD + lane];
  float bb = bias[lane];
  for (int n = wid; n < NN; n += NWAVE) {
    const float* row = h + n * HD;            // wave-uniform -> s_load
    float a0 = 0.f, a1 = 0.f, a2 = 0.f, a3 = 0.f;
    #pragma unroll
    for (int k = 0; k < HD; k += 4) {
      a0 = fmaf(row[k + 0], w[k + 0], a0);
      a1 = fmaf(row[k + 1], w[k + 1], a1);
      a2 = fmaf(row[k + 2], w[k + 2], a2);
      a3 = fmaf(row[k + 3], w[k + 3], a3);
    }
    hnext[n * HD + lane] = bb + ((a0 + a1) + (a2 + a3));
  }
}

// edge messages: hnext[dst] += h[src] @ W_{type}; wave per edge, W in VGPRs.
__device__ __forceinline__ void msg_phase(const int* __restrict__ srcs,
    const int* __restrict__ dsts, const int* __restrict__ offs,
    const float* __restrict__ Wty, const float* __restrict__ h,
    float* __restrict__ hnext, int lane) {
  int wid = __builtin_amdgcn_readfirstlane(blockIdx.x * 4 + (threadIdx.x >> 6));
  const int per = (NE + NWAVE - 1) / NWAVE;
  int beg = wid * per;
  int end = beg + per; if (end > NE) end = NE;
  if (beg >= end) return;
  for (int t = 0; t < EDIM; ++t) {
    int lo = offs[t];     if (lo < beg) lo = beg;
    int hi = offs[t + 1]; if (hi > end) hi = end;
    if (lo >= hi) continue;
    float w[HD];
    #pragma unroll
    for (int k = 0; k < HD; ++k) w[k] = Wty[t * 4096 + k * HD + lane];
    for (int p = lo; p < hi; ++p) {
      int s = __builtin_amdgcn_readfirstlane(srcs[p]);
      int d = __builtin_amdgcn_readfirstlane(dsts[p]);
      const float* row = h + s * HD;          // wave-uniform -> s_load
      float a0 = 0.f, a1 = 0.f, a2 = 0.f, a3 = 0.f;
      #pragma unroll
      for (int k = 0; k < HD; k += 4) {
        a0 = fmaf(row[k + 0], w[k + 0], a0);
        a1 = fmaf(row[k + 1], w[k + 1], a1);
        a2 = fmaf(row[k + 2], w[k + 2], a2);
        a3 = fmaf(row[k + 3], w[k + 3], a3);
      }
      atomicAdd(&hnext[d * HD + lane], (a0 + a1) + (a2 + a3));
    }
  }
}

__global__ __launch_bounds__(256, 2) void mega(
    const float* __restrict__ node_feat, const int* __restrict__ node_type,
    const int* __restrict__ edge_index, const int* __restrict__ edge_type,
    const int* __restrict__ batch,
    const float* __restrict__ W_emb, const float* __restrict__ b_emb,
    const float* __restrict__ W_e1, const float* __restrict__ b_e1,
    const float* __restrict__ W_e2, const float* __restrict__ b_e2,
    const float* __restrict__ roots, const float* __restrict__ conv_bias,
    const float* __restrict__ W_ih, const float* __restrict__ W_hh,
    const float* __restrict__ b_ih, const float* __restrict__ b_hh,
    const float* __restrict__ W_o1, const float* __restrict__ b_o1,
    const float* __restrict__ W_o2, const float* __restrict__ b_o2,
    float* __restrict__ out,
    float* __restrict__ Wty, float* __restrict__ hA, float* __restrict__ hB,
    float* __restrict__ W_ihT, float* __restrict__ W_hhT,
    int* __restrict__ srcs, int* __restrict__ dsts,
    int* __restrict__ bc, int* __restrict__ bbase,
    int* __restrict__ offs, int* __restrict__ gstart, int* bar) {
  __shared__ SharedU sh;
  int b = blockIdx.x, tid = threadIdx.x;
  int lane = tid & 63, wv = tid >> 6;

  // ======== P0: embed (all) || edgemats || wT || cnt || starts ========
  {
    int wid = __builtin_amdgcn_readfirstlane(b * 4 + wv);
    for (int n = wid; n < NN; n += NWAVE) {
      int t = __builtin_amdgcn_readfirstlane(node_type[n]);
      const float* row = node_feat + n * NFEAT;     // wave-uniform -> s_load
      float acc = b_emb[lane] + W_emb[t * HD + lane];
      #pragma unroll
      for (int f = 0; f < NFEAT; ++f)
        acc = fmaf(row[f], W_emb[(NTYPES + f) * HD + lane], acc);
      hA[n * HD + lane] = acc;
    }
  }
  if (b < 20) {
    // 5 edge-type matrices: Wty[t] = relu(W_e1[t]+b_e1) @ W_e2 + b_e2
    int t = b >> 2, chunk = b & 3;
    if (tid < HD) {
      float x = W_e1[t * HD + tid] + b_e1[tid];
      sh.emv[tid] = x > 0.f ? x : 0.f;
    }
    __syncthreads();
    #pragma unroll
    for (int i = 0; i < 4; ++i) {
      int m = chunk * 1024 + i * 256 + tid;
      float acc = b_e2[m];
      #pragma unroll
      for (int j = 0; j < HD; ++j)
        acc = fmaf(sh.emv[j], W_e2[j * 4096 + m], acc);
      Wty[t * 4096 + m] = acc;
    }
  } else if (b < 148) {
    // LSTM weight transpose
    int idx = (b - 20) * 256 + tid;                 // 0..32767
    { int g = idx >> 7, j = idx & 127; W_ihT[j * 256 + g] = W_ih[idx]; }
    if (idx < 4 * HD * HD) {
      int g = idx >> 6, j = idx & 63;
      W_hhT[j * 256 + g] = W_hh[idx];
    }
  } else if (b < 148 + NBLK) {
    // ballot per-block type counts
    int e = (b - 148) * 256 + tid;
    int ty = (e < NE) ? edge_type[e] : -1;
    #pragma unroll
    for (int t = 0; t < EDIM; ++t) {
      unsigned long long m = __ballot(ty == t);
      if (lane == 0) sh.wc[wv][t] = __popcll(m);
    }
    __syncthreads();
    if (tid < EDIM) {
      int s = 0;
      #pragma unroll
      for (int w = 0; w < 4; ++w) s += sh.wc[w][tid];
      bc[(b - 148) * EDIM + tid] = s;
    }
  } else if (b < 148 + NBLK + NSB) {
    // CSR starts of sorted batch vector
    int n = (b - 148 - NBLK) * 256 + tid;
    if (n < NN) {
      int bb = batch[n];
      if (n == 0)
        for (int t = 0; t <= bb; ++t) gstart[t] = 0;
      int bn = (n + 1 < NN) ? batch[n + 1] : NB;
      for (int t = bb + 1; t <= bn; ++t) gstart[t] = n + 1;
    }
  }
  gsync(bar, 0);

  // ======== P1: scan over block counts (block 0) ========
  if (b == 0) {
    int running = 0;
    for (int t = 0; t < EDIM; ++t) {
      int v = (tid < NBLK) ? bc[tid * EDIM + t] : 0;
      sh.scanbuf[tid] = v;
      __syncthreads();
      #pragma unroll
      for (int off = 1; off < 256; off <<= 1) {
        int x = (tid >= off) ? sh.scanbuf[tid - off] : 0;
        __syncthreads();
        sh.scanbuf[tid] += x;
        __syncthreads();
      }
      int incl = sh.scanbuf[tid];
      int total = sh.scanbuf[255];
      if (tid < NBLK) bbase[tid * EDIM + t] = running + incl - v;
      if (tid == 0) offs[t] = running;
      running += total;
      __syncthreads();
    }
    if (tid == 0) offs[EDIM] = running;
  }
  gsync(bar, 1);

  // ======== P2: place (blocks<NBLK) + root iter0 (all) ========
  if (b < NBLK) {
    int e = b * 256 + tid;
    int ty = (e < NE) ? edge_type[e] : -1;
    int rank = 0;
    #pragma unroll
    for (int t = 0; t < EDIM; ++t) {
      unsigned long long m = __ballot(ty == t);
      if (lane == 0) sh.wc[wv][t] = __popcll(m);
      if (ty == t) rank = __popcll(m & ((1ull << lane) - 1ull));
    }
    __syncthreads();
    if (ty >= 0) {
      int base = bbase[b * EDIM + ty];
      for (int w = 0; w < wv; ++w) base += sh.wc[w][ty];
      int pos = base + rank;
      srcs[pos] = edge_index[e];
      dsts[pos] = edge_index[NE + e];
    }
  }
  root_phase(hA, hB, roots, conv_bias, lane);
  gsync(bar, 2);

  // ======== MP iterations ========
  msg_phase(srcs, dsts, offs, Wty, hA, hB, lane);
  gsync(bar, 3);
  root_phase(hB, hA, roots + 4096, conv_bias + HD, lane);
  gsync(bar, 4);
  msg_phase(srcs, dsts, offs, Wty, hB, hA, lane);
  gsync(bar, 5);
  root_phase(hA, hB, roots + 8192, conv_bias + 2 * HD, lane);
  gsync(bar, 6);
  msg_phase(srcs, dsts, offs, Wty, hA, hB, lane);
  gsync(bar, 7);

  // ======== P8: Set2Set + output MLP (blocks < NB), h = hB ========
  if (b >= NB) return;
  const float* __restrict__ h = hB;
  int st = gstart[b], en = gstart[b + 1];
  int cnt = en - st;
  int cached = cnt < SMAX ? cnt : SMAX;

  // stage node block into padded LDS
  int total = cached * HD;
  for (int base = tid * 4; base < total; base += 1024) {
    float4 v = *reinterpret_cast<const float4*>(h + st * HD + base);
    int n = base >> 6, k = base & 63;
    float* row = sh.s.hs + n * HP + k;
    row[0] = v.x; row[1] = v.y; row[2] = v.z; row[3] = v.w;
  }
  if (tid < 2 * HD) sh.s.qstar[tid] = 0.f;
  if (tid < HD) { sh.s.hxs[tid] = 0.f; sh.s.cxs[tid] = 0.f; }
  __syncthreads();

  for (int it = 0; it < S2SIT; ++it) {
    // LSTM gates via transposed weights (coalesced): tid = gate index
    float acc0 = b_ih[tid] + b_hh[tid], acc1 = 0.f;
    #pragma unroll 8
    for (int j = 0; j < 2 * HD; j += 2) {
      acc0 = fmaf(sh.s.qstar[j],     W_ihT[j * 256 + tid],       acc0);
      acc1 = fmaf(sh.s.qstar[j + 1], W_ihT[(j + 1) * 256 + tid], acc1);
    }
    #pragma unroll 8
    for (int j = 0; j < HD; j += 2) {
      acc0 = fmaf(sh.s.hxs[j],     W_hhT[j * 256 + tid],       acc0);
      acc1 = fmaf(sh.s.hxs[j + 1], W_hhT[(j + 1) * 256 + tid], acc1);
    }
    sh.s.gates[tid] = acc0 + acc1;
    __syncthreads();
    if (tid < HD) {
      float ig = sigm(sh.s.gates[tid]);
      float fg = sigm(sh.s.gates[HD + tid]);
      float gg = tanhf(sh.s.gates[2 * HD + tid]);
      float og = sigm(sh.s.gates[3 * HD + tid]);
      float c = fmaf(fg, sh.s.cxs[tid], ig * gg);
      sh.s.cxs[tid] = c;
      sh.s.hxs[tid] = og * tanhf(c);
    }
    __syncthreads();

    // pass 1: per-thread dot (thread = node), padded LDS (conflict-free)
    float e = -1e30f;
    if (tid < cached) {
      const float* row = sh.s.hs + tid * HP;
      float d0 = 0.f, d1 = 0.f;
      #pragma unroll 8
      for (int k = 0; k < HD; k += 2) {
        d0 = fmaf(row[k],     sh.s.hxs[k],     d0);
        d1 = fmaf(row[k + 1], sh.s.hxs[k + 1], d1);
      }
      e = d0 + d1;
      sh.s.ebuf[tid] = e;
    }
    float m = e;
    #pragma unroll
    for (int off = 32; off; off >>= 1) m = fmaxf(m, __shfl_xor(m, off, 64));
    float qreg = sh.s.hxs[lane];
    for (int n = cached + wv; n < cnt; n += 4) {   // overflow tail
      float ev = h[(st + n) * HD + lane] * qreg;
      #pragma unroll
      for (int off = 32; off; off >>= 1) ev += __shfl_xor(ev, off, 64);
      m = fmaxf(m, ev);
    }
    if (lane == 0) sh.s.redM[wv] = m;
    __syncthreads();
    float M = fmaxf(fmaxf(sh.s.redM[0], sh.s.redM[1]),
                    fmaxf(sh.s.redM[2], sh.s.redM[3]));

    // pass 2a: a = exp(e-M), per-wave partial sum
    float sp = 0.f;
    if (tid < cached) {
      float a = expf(sh.s.ebuf[tid] - M);
      sh.s.ebuf[tid] = a;
      sp = a;
    }
    #pragma unroll
    for (int off = 32; off; off >>= 1) sp += __shfl_xor(sp, off, 64);
    __syncthreads();

    // pass 2b: r = sum_n a[n] * h_n  (lane = feature)
    float r = 0.f;
    for (int n = wv; n < cached; n += 4)
      r = fmaf(sh.s.ebuf[n], sh.s.hs[n * HP + lane], r);
    float s_tail = 0.f;
    for (int n = cached + wv; n < cnt; n += 4) {   // overflow tail
      float v = h[(st + n) * HD + lane];
      float ev = v * qreg;
      #pragma unroll
      for (int off = 32; off; off >>= 1) ev += __shfl_xor(ev, off, 64);
      float a = expf(ev - M);
      s_tail += a;
      r = fmaf(a, v, r);
    }
    if (lane == 0) sh.s.redS[wv] = sp + s_tail;
    sh.s.redR[wv][lane] = r;
    __syncthreads();
    if (tid < HD) {
      float S = sh.s.redS[0] + sh.s.redS[1] + sh.s.redS[2] + sh.s.redS[3];
      float R = sh.s.redR[0][tid] + sh.s.redR[1][tid] +
                sh.s.redR[2][tid] + sh.s.redR[3][tid];
      if (S == 0.f) S = 1.f;            // empty-graph guard (matches ref)
      sh.s.qstar[tid] = sh.s.hxs[tid];
      sh.s.qstar[HD + tid] = R / S;
    }
    __syncthreads();
  }

  // output MLP: relu(qstar @ W_o1 + b_o1) @ W_o2 + b_o2
  if (tid < HD) {
    float acc = b_o1[tid];
    #pragma unroll 8
    for (int i = 0; i < 2 * HD; ++i)
      acc = fmaf(sh.s.qstar[i], W_o1[i * HD + tid], acc);
    sh.s.hid[tid] = acc > 0.f ? acc : 0.f;
  }
  __syncthreads();
  if (tid < HD) {
    float p = sh.s.hid[tid] * W_o2[tid];
    #pragma unroll
    for (int off = 32; off; off >>= 1) p += __shfl_xor(p, off, 64);
    if (tid == 0) out[b] = p + b_o2[0];
  }
}

extern "C" void kernel_launch(void* const* d_in, const int* in_sizes, int n_in,
                              void* d_out, int out_size, void* d_ws, size_t ws_size,
                              hipStream_t stream) {
  const float* node_feat = (const float*)d_in[0];
  const int*   node_type = (const int*)d_in[1];
  const int*   edge_index= (const int*)d_in[2];
  const int*   edge_type = (const int*)d_in[3];
  const int*   batch     = (const int*)d_in[4];
  const float* W_emb     = (const float*)d_in[5];
  const float* b_emb     = (const float*)d_in[6];
  const float* W_e1      = (const float*)d_in[7];
  const float* b_e1      = (const float*)d_in[8];
  const float* W_e2      = (const float*)d_in[9];
  const float* b_e2      = (const float*)d_in[10];
  const float* roots     = (const float*)d_in[11];
  const float* conv_bias = (const float*)d_in[12];
  const float* W_ih      = (const float*)d_in[13];
  const float* W_hh      = (const float*)d_in[14];
  const float* b_ih      = (const float*)d_in[15];
  const float* b_hh      = (const float*)d_in[16];
  const float* W_o1      = (const float*)d_in[17];
  const float* b_o1      = (const float*)d_in[18];
  const float* W_o2      = (const float*)d_in[19];
  const float* b_o2      = (const float*)d_in[20];
  float* out = (float*)d_out;

  float* Wty    = (float*)d_ws;                 // 5*4096
  float* hA     = Wty + EDIM * 4096;            // NN*64
  float* hB     = hA + NN * HD;                 // NN*64
  float* W_ihT  = hB + NN * HD;                 // 128*256
  float* W_hhT  = W_ihT + 2 * HD * 4 * HD;      // 64*256
  int*   srcs   = (int*)(W_hhT + HD * 4 * HD);  // NE
  int*   dsts   = srcs + NE;                    // NE
  int*   bc     = dsts + NE;                    // NBLK*EDIM
  int*   bbase  = bc + NBLK * EDIM;             // NBLK*EDIM
  int*   offs   = bbase + NBLK * EDIM;          // EDIM+1 (pad 8)
  int*   gstart = offs + 8;                     // NB+1 (pad 136)
  int*   bar    = gstart + 136;                 // 2 ints (barrier state)

  hipMemsetAsync(bar, 0, 2 * sizeof(int), stream);

  mega<<<dim3(GRID), dim3(256), 0, stream>>>(
      node_feat, node_type, edge_index, edge_type, batch,
      W_emb, b_emb, W_e1, b_e1, W_e2, b_e2, roots, conv_bias,
      W_ih, W_hh, b_ih, b_hh, W_o1, b_o1, W_o2, b_o2, out,
      Wty, hA, hB, W_ihT, W_hhT, srcs, dsts, bc, bbase, offs, gstart, bar);
}

// Round 8
// 588.194 us; speedup vs baseline: 1.7467x; 1.7467x over previous
//
#include <hip/hip_runtime.h>
#include <math.h>

// ---------------------------------------------------------------------------
// MPNNPropPred, R8: persistent mega-kernel (R7) with FIXED software barrier.
// R7's gsync polled with ACQUIRE atomic loads -> buffer_inv (L1+L2 invalidate)
// per poll iteration -> L2 invalidation storm -> 30MB HBM refetch, 942us.
// R8: RELEASE on arrival, RELAXED polls (no cache maintenance), ONE ACQUIRE
// load after the spin exits (single buffer_inv per block per barrier).
// 512 blocks x 256 thr; LDS 62976B -> 2 blocks/CU; all blocks co-resident.
// ---------------------------------------------------------------------------

#define NN 20000
#define NE 50000
#define NB 128
#define HD 64
#define NFEAT 28
#define NTYPES 100
#define EDIM 5
#define S2SIT 4
#define NBLK 196                  // ceil(NE/256)
#define NSB 79                    // ceil(NN/256)
#define SMAX 224
#define HP (HD + 1)
#define GRID 512
#define NWAVE (GRID * 4)

struct S2SM {
  float hs[SMAX * HP];
  float ebuf[SMAX];
  float qstar[2 * HD];
  float hxs[HD], cxs[HD], gates[4 * HD];
  float redM[4], redS[4], redR[4][HD];
  float hid[HD];
};
union SharedU {
  S2SM s;
  int scanbuf[256];
  int wc[4][EDIM];
  float emv[HD];
};

__device__ __forceinline__ float sigm(float x) {
  return 1.0f / (1.0f + expf(-x));
}

// software grid barrier, cumulative arrival counter.
// RELEASE arrival (wbl2, no inv) -> RELAXED spin (no cache maintenance)
// -> single ACQUIRE load on exit (one buffer_inv per block per barrier).
__device__ __forceinline__ void gsync(int* bar, int phase) {
  __syncthreads();
  if (threadIdx.x == 0) {
    __hip_atomic_fetch_add(&bar[0], 1, __ATOMIC_RELEASE,
                           __HIP_MEMORY_SCOPE_AGENT);
    const int target = GRID * (phase + 1);
    while (__hip_atomic_load(&bar[0], __ATOMIC_RELAXED,
                             __HIP_MEMORY_SCOPE_AGENT) < target)
      __builtin_amdgcn_s_sleep(16);
    (void)__hip_atomic_load(&bar[0], __ATOMIC_ACQUIRE,
                            __HIP_MEMORY_SCOPE_AGENT);
  }
  __syncthreads();
}

// root: hnext[n][o] = bias[o] + sum_k h[n][k]*root[k][o] (inits hnext)
__device__ __forceinline__ void root_phase(const float* __restrict__ h,
    float* __restrict__ hnext, const float* __restrict__ root,
    const float* __restrict__ bias, int lane) {
  int wid = __builtin_amdgcn_readfirstlane(blockIdx.x * 4 + (threadIdx.x >> 6));
  float w[HD];
  #pragma unroll
  for (int k = 0; k < HD; ++k) w[k] = root[k * HD + lane];
  float bb = bias[lane];
  for (int n = wid; n < NN; n += NWAVE) {
    const float* row = h + n * HD;            // wave-uniform -> s_load
    float a0 = 0.f, a1 = 0.f, a2 = 0.f, a3 = 0.f;
    #pragma unroll
    for (int k = 0; k < HD; k += 4) {
      a0 = fmaf(row[k + 0], w[k + 0], a0);
      a1 = fmaf(row[k + 1], w[k + 1], a1);
      a2 = fmaf(row[k + 2], w[k + 2], a2);
      a3 = fmaf(row[k + 3], w[k + 3], a3);
    }
    hnext[n * HD + lane] = bb + ((a0 + a1) + (a2 + a3));
  }
}

// edge messages: hnext[dst] += h[src] @ W_{type}; wave per edge, W in VGPRs.
__device__ __forceinline__ void msg_phase(const int* __restrict__ srcs,
    const int* __restrict__ dsts, const int* __restrict__ offs,
    const float* __restrict__ Wty, const float* __restrict__ h,
    float* __restrict__ hnext, int lane) {
  int wid = __builtin_amdgcn_readfirstlane(blockIdx.x * 4 + (threadIdx.x >> 6));
  const int per = (NE + NWAVE - 1) / NWAVE;
  int beg = wid * per;
  int end = beg + per; if (end > NE) end = NE;
  if (beg >= end) return;
  for (int t = 0; t < EDIM; ++t) {
    int lo = offs[t];     if (lo < beg) lo = beg;
    int hi = offs[t + 1]; if (hi > end) hi = end;
    if (lo >= hi) continue;
    float w[HD];
    #pragma unroll
    for (int k = 0; k < HD; ++k) w[k] = Wty[t * 4096 + k * HD + lane];
    for (int p = lo; p < hi; ++p) {
      int s = __builtin_amdgcn_readfirstlane(srcs[p]);
      int d = __builtin_amdgcn_readfirstlane(dsts[p]);
      const float* row = h + s * HD;          // wave-uniform -> s_load
      float a0 = 0.f, a1 = 0.f, a2 = 0.f, a3 = 0.f;
      #pragma unroll
      for (int k = 0; k < HD; k += 4) {
        a0 = fmaf(row[k + 0], w[k + 0], a0);
        a1 = fmaf(row[k + 1], w[k + 1], a1);
        a2 = fmaf(row[k + 2], w[k + 2], a2);
        a3 = fmaf(row[k + 3], w[k + 3], a3);
      }
      atomicAdd(&hnext[d * HD + lane], (a0 + a1) + (a2 + a3));
    }
  }
}

__global__ __launch_bounds__(256, 2) void mega(
    const float* __restrict__ node_feat, const int* __restrict__ node_type,
    const int* __restrict__ edge_index, const int* __restrict__ edge_type,
    const int* __restrict__ batch,
    const float* __restrict__ W_emb, const float* __restrict__ b_emb,
    const float* __restrict__ W_e1, const float* __restrict__ b_e1,
    const float* __restrict__ W_e2, const float* __restrict__ b_e2,
    const float* __restrict__ roots, const float* __restrict__ conv_bias,
    const float* __restrict__ W_ih, const float* __restrict__ W_hh,
    const float* __restrict__ b_ih, const float* __restrict__ b_hh,
    const float* __restrict__ W_o1, const float* __restrict__ b_o1,
    const float* __restrict__ W_o2, const float* __restrict__ b_o2,
    float* __restrict__ out,
    float* __restrict__ Wty, float* __restrict__ hA, float* __restrict__ hB,
    float* __restrict__ W_ihT, float* __restrict__ W_hhT,
    int* __restrict__ srcs, int* __restrict__ dsts,
    int* __restrict__ bc, int* __restrict__ bbase,
    int* __restrict__ offs, int* __restrict__ gstart, int* bar) {
  __shared__ SharedU sh;
  int b = blockIdx.x, tid = threadIdx.x;
  int lane = tid & 63, wv = tid >> 6;

  // ======== P0: embed (all) || edgemats || wT || cnt || starts ========
  {
    int wid = __builtin_amdgcn_readfirstlane(b * 4 + wv);
    for (int n = wid; n < NN; n += NWAVE) {
      int t = __builtin_amdgcn_readfirstlane(node_type[n]);
      const float* row = node_feat + n * NFEAT;     // wave-uniform -> s_load
      float acc = b_emb[lane] + W_emb[t * HD + lane];
      #pragma unroll
      for (int f = 0; f < NFEAT; ++f)
        acc = fmaf(row[f], W_emb[(NTYPES + f) * HD + lane], acc);
      hA[n * HD + lane] = acc;
    }
  }
  if (b < 20) {
    // 5 edge-type matrices: Wty[t] = relu(W_e1[t]+b_e1) @ W_e2 + b_e2
    int t = b >> 2, chunk = b & 3;
    if (tid < HD) {
      float x = W_e1[t * HD + tid] + b_e1[tid];
      sh.emv[tid] = x > 0.f ? x : 0.f;
    }
    __syncthreads();
    #pragma unroll
    for (int i = 0; i < 4; ++i) {
      int m = chunk * 1024 + i * 256 + tid;
      float acc = b_e2[m];
      #pragma unroll
      for (int j = 0; j < HD; ++j)
        acc = fmaf(sh.emv[j], W_e2[j * 4096 + m], acc);
      Wty[t * 4096 + m] = acc;
    }
  } else if (b < 148) {
    // LSTM weight transpose
    int idx = (b - 20) * 256 + tid;                 // 0..32767
    { int g = idx >> 7, j = idx & 127; W_ihT[j * 256 + g] = W_ih[idx]; }
    if (idx < 4 * HD * HD) {
      int g = idx >> 6, j = idx & 63;
      W_hhT[j * 256 + g] = W_hh[idx];
    }
  } else if (b < 148 + NBLK) {
    // ballot per-block type counts
    int e = (b - 148) * 256 + tid;
    int ty = (e < NE) ? edge_type[e] : -1;
    #pragma unroll
    for (int t = 0; t < EDIM; ++t) {
      unsigned long long m = __ballot(ty == t);
      if (lane == 0) sh.wc[wv][t] = __popcll(m);
    }
    __syncthreads();
    if (tid < EDIM) {
      int s = 0;
      #pragma unroll
      for (int w = 0; w < 4; ++w) s += sh.wc[w][tid];
      bc[(b - 148) * EDIM + tid] = s;
    }
  } else if (b < 148 + NBLK + NSB) {
    // CSR starts of sorted batch vector
    int n = (b - 148 - NBLK) * 256 + tid;
    if (n < NN) {
      int bb = batch[n];
      if (n == 0)
        for (int t = 0; t <= bb; ++t) gstart[t] = 0;
      int bn = (n + 1 < NN) ? batch[n + 1] : NB;
      for (int t = bb + 1; t <= bn; ++t) gstart[t] = n + 1;
    }
  }
  gsync(bar, 0);

  // ======== P1: scan over block counts (block 0) ========
  if (b == 0) {
    int running = 0;
    for (int t = 0; t < EDIM; ++t) {
      int v = (tid < NBLK) ? bc[tid * EDIM + t] : 0;
      sh.scanbuf[tid] = v;
      __syncthreads();
      #pragma unroll
      for (int off = 1; off < 256; off <<= 1) {
        int x = (tid >= off) ? sh.scanbuf[tid - off] : 0;
        __syncthreads();
        sh.scanbuf[tid] += x;
        __syncthreads();
      }
      int incl = sh.scanbuf[tid];
      int total = sh.scanbuf[255];
      if (tid < NBLK) bbase[tid * EDIM + t] = running + incl - v;
      if (tid == 0) offs[t] = running;
      running += total;
      __syncthreads();
    }
    if (tid == 0) offs[EDIM] = running;
  }
  gsync(bar, 1);

  // ======== P2: place (blocks<NBLK) + root iter0 (all) ========
  if (b < NBLK) {
    int e = b * 256 + tid;
    int ty = (e < NE) ? edge_type[e] : -1;
    int rank = 0;
    #pragma unroll
    for (int t = 0; t < EDIM; ++t) {
      unsigned long long m = __ballot(ty == t);
      if (lane == 0) sh.wc[wv][t] = __popcll(m);
      if (ty == t) rank = __popcll(m & ((1ull << lane) - 1ull));
    }
    __syncthreads();
    if (ty >= 0) {
      int base = bbase[b * EDIM + ty];
      for (int w = 0; w < wv; ++w) base += sh.wc[w][ty];
      int pos = base + rank;
      srcs[pos] = edge_index[e];
      dsts[pos] = edge_index[NE + e];
    }
  }
  root_phase(hA, hB, roots, conv_bias, lane);
  gsync(bar, 2);

  // ======== MP iterations ========
  msg_phase(srcs, dsts, offs, Wty, hA, hB, lane);
  gsync(bar, 3);
  root_phase(hB, hA, roots + 4096, conv_bias + HD, lane);
  gsync(bar, 4);
  msg_phase(srcs, dsts, offs, Wty, hB, hA, lane);
  gsync(bar, 5);
  root_phase(hA, hB, roots + 8192, conv_bias + 2 * HD, lane);
  gsync(bar, 6);
  msg_phase(srcs, dsts, offs, Wty, hA, hB, lane);
  gsync(bar, 7);

  // ======== P8: Set2Set + output MLP (blocks < NB), h = hB ========
  if (b >= NB) return;
  const float* __restrict__ h = hB;
  int st = gstart[b], en = gstart[b + 1];
  int cnt = en - st;
  int cached = cnt < SMAX ? cnt : SMAX;

  // stage node block into padded LDS
  int total = cached * HD;
  for (int base = tid * 4; base < total; base += 1024) {
    float4 v = *reinterpret_cast<const float4*>(h + st * HD + base);
    int n = base >> 6, k = base & 63;
    float* row = sh.s.hs + n * HP + k;
    row[0] = v.x; row[1] = v.y; row[2] = v.z; row[3] = v.w;
  }
  if (tid < 2 * HD) sh.s.qstar[tid] = 0.f;
  if (tid < HD) { sh.s.hxs[tid] = 0.f; sh.s.cxs[tid] = 0.f; }
  __syncthreads();

  for (int it = 0; it < S2SIT; ++it) {
    // LSTM gates via transposed weights (coalesced): tid = gate index
    float acc0 = b_ih[tid] + b_hh[tid], acc1 = 0.f;
    #pragma unroll 8
    for (int j = 0; j < 2 * HD; j += 2) {
      acc0 = fmaf(sh.s.qstar[j],     W_ihT[j * 256 + tid],       acc0);
      acc1 = fmaf(sh.s.qstar[j + 1], W_ihT[(j + 1) * 256 + tid], acc1);
    }
    #pragma unroll 8
    for (int j = 0; j < HD; j += 2) {
      acc0 = fmaf(sh.s.hxs[j],     W_hhT[j * 256 + tid],       acc0);
      acc1 = fmaf(sh.s.hxs[j + 1], W_hhT[(j + 1) * 256 + tid], acc1);
    }
    sh.s.gates[tid] = acc0 + acc1;
    __syncthreads();
    if (tid < HD) {
      float ig = sigm(sh.s.gates[tid]);
      float fg = sigm(sh.s.gates[HD + tid]);
      float gg = tanhf(sh.s.gates[2 * HD + tid]);
      float og = sigm(sh.s.gates[3 * HD + tid]);
      float c = fmaf(fg, sh.s.cxs[tid], ig * gg);
      sh.s.cxs[tid] = c;
      sh.s.hxs[tid] = og * tanhf(c);
    }
    __syncthreads();

    // pass 1: per-thread dot (thread = node), padded LDS (conflict-free)
    float e = -1e30f;
    if (tid < cached) {
      const float* row = sh.s.hs + tid * HP;
      float d0 = 0.f, d1 = 0.f;
      #pragma unroll 8
      for (int k = 0; k < HD; k += 2) {
        d0 = fmaf(row[k],     sh.s.hxs[k],     d0);
        d1 = fmaf(row[k + 1], sh.s.hxs[k + 1], d1);
      }
      e = d0 + d1;
      sh.s.ebuf[tid] = e;
    }
    float m = e;
    #pragma unroll
    for (int off = 32; off; off >>= 1) m = fmaxf(m, __shfl_xor(m, off, 64));
    float qreg = sh.s.hxs[lane];
    for (int n = cached + wv; n < cnt; n += 4) {   // overflow tail
      float ev = h[(st + n) * HD + lane] * qreg;
      #pragma unroll
      for (int off = 32; off; off >>= 1) ev += __shfl_xor(ev, off, 64);
      m = fmaxf(m, ev);
    }
    if (lane == 0) sh.s.redM[wv] = m;
    __syncthreads();
    float M = fmaxf(fmaxf(sh.s.redM[0], sh.s.redM[1]),
                    fmaxf(sh.s.redM[2], sh.s.redM[3]));

    // pass 2a: a = exp(e-M), per-wave partial sum
    float sp = 0.f;
    if (tid < cached) {
      float a = expf(sh.s.ebuf[tid] - M);
      sh.s.ebuf[tid] = a;
      sp = a;
    }
    #pragma unroll
    for (int off = 32; off; off >>= 1) sp += __shfl_xor(sp, off, 64);
    __syncthreads();

    // pass 2b: r = sum_n a[n] * h_n  (lane = feature)
    float r = 0.f;
    for (int n = wv; n < cached; n += 4)
      r = fmaf(sh.s.ebuf[n], sh.s.hs[n * HP + lane], r);
    float s_tail = 0.f;
    for (int n = cached + wv; n < cnt; n += 4) {   // overflow tail
      float v = h[(st + n) * HD + lane];
      float ev = v * qreg;
      #pragma unroll
      for (int off = 32; off; off >>= 1) ev += __shfl_xor(ev, off, 64);
      float a = expf(ev - M);
      s_tail += a;
      r = fmaf(a, v, r);
    }
    if (lane == 0) sh.s.redS[wv] = sp + s_tail;
    sh.s.redR[wv][lane] = r;
    __syncthreads();
    if (tid < HD) {
      float S = sh.s.redS[0] + sh.s.redS[1] + sh.s.redS[2] + sh.s.redS[3];
      float R = sh.s.redR[0][tid] + sh.s.redR[1][tid] +
                sh.s.redR[2][tid] + sh.s.redR[3][tid];
      if (S == 0.f) S = 1.f;            // empty-graph guard (matches ref)
      sh.s.qstar[tid] = sh.s.hxs[tid];
      sh.s.qstar[HD + tid] = R / S;
    }
    __syncthreads();
  }

  // output MLP: relu(qstar @ W_o1 + b_o1) @ W_o2 + b_o2
  if (tid < HD) {
    float acc = b_o1[tid];
    #pragma unroll 8
    for (int i = 0; i < 2 * HD; ++i)
      acc = fmaf(sh.s.qstar[i], W_o1[i * HD + tid], acc);
    sh.s.hid[tid] = acc > 0.f ? acc : 0.f;
  }
  __syncthreads();
  if (tid < HD) {
    float p = sh.s.hid[tid] * W_o2[tid];
    #pragma unroll
    for (int off = 32; off; off >>= 1) p += __shfl_xor(p, off, 64);
    if (tid == 0) out[b] = p + b_o2[0];
  }
}

extern "C" void kernel_launch(void* const* d_in, const int* in_sizes, int n_in,
                              void* d_out, int out_size, void* d_ws, size_t ws_size,
                              hipStream_t stream) {
  const float* node_feat = (const float*)d_in[0];
  const int*   node_type = (const int*)d_in[1];
  const int*   edge_index= (const int*)d_in[2];
  const int*   edge_type = (const int*)d_in[3];
  const int*   batch     = (const int*)d_in[4];
  const float* W_emb     = (const float*)d_in[5];
  const float* b_emb     = (const float*)d_in[6];
  const float* W_e1      = (const float*)d_in[7];
  const float* b_e1      = (const float*)d_in[8];
  const float* W_e2      = (const float*)d_in[9];
  const float* b_e2      = (const float*)d_in[10];
  const float* roots     = (const float*)d_in[11];
  const float* conv_bias = (const float*)d_in[12];
  const float* W_ih      = (const float*)d_in[13];
  const float* W_hh      = (const float*)d_in[14];
  const float* b_ih      = (const float*)d_in[15];
  const float* b_hh      = (const float*)d_in[16];
  const float* W_o1      = (const float*)d_in[17];
  const float* b_o1      = (const float*)d_in[18];
  const float* W_o2      = (const float*)d_in[19];
  const float* b_o2      = (const float*)d_in[20];
  float* out = (float*)d_out;

  float* Wty    = (float*)d_ws;                 // 5*4096
  float* hA     = Wty + EDIM * 4096;            // NN*64
  float* hB     = hA + NN * HD;                 // NN*64
  float* W_ihT  = hB + NN * HD;                 // 128*256
  float* W_hhT  = W_ihT + 2 * HD * 4 * HD;      // 64*256
  int*   srcs   = (int*)(W_hhT + HD * 4 * HD);  // NE
  int*   dsts   = srcs + NE;                    // NE
  int*   bc     = dsts + NE;                    // NBLK*EDIM
  int*   bbase  = bc + NBLK * EDIM;             // NBLK*EDIM
  int*   offs   = bbase + NBLK * EDIM;          // EDIM+1 (pad 8)
  int*   gstart = offs + 8;                     // NB+1 (pad 136)
  int*   bar    = gstart + 136;                 // 2 ints (barrier state)

  hipMemsetAsync(bar, 0, 2 * sizeof(int), stream);

  mega<<<dim3(GRID), dim3(256), 0, stream>>>(
      node_feat, node_type, edge_index, edge_type, batch,
      W_emb, b_emb, W_e1, b_e1, W_e2, b_e2, roots, conv_bias,
      W_ih, W_hh, b_ih, b_hh, W_o1, b_o1, W_o2, b_o2, out,
      Wty, hA, hB, W_ihT, W_hhT, srcs, dsts, bc, bbase, offs, gstart, bar);
}

// Round 9
// 281.379 us; speedup vs baseline: 3.6513x; 2.0904x over previous
//
#include <hip/hip_runtime.h>
#include <math.h>

// ---------------------------------------------------------------------------
// MPNNPropPred, R9: back to multi-kernel (persistent kernel falsified: R7/R8
// coherence-point latency 505-942us). R4 kernel bodies, but 14 -> 9 dispatches:
//   k_setup  (edgemats | wT | cnt | starts roles + grid-strided embed)
//   k_place  (per-block LDS rescan of bc -> base; block0 writes offs; place)
//   [k_root, k_msg] x3   (unchanged from R4)
//   k_s2s                (unchanged from R4)
// N=20000, E=50000, B=128, H=64. All f32.
// ---------------------------------------------------------------------------

#define NN 20000
#define NE 50000
#define NB 128
#define HD 64
#define NFEAT 28
#define NTYPES 100
#define EDIM 5
#define S2SIT 4
#define NBLK 196                  // ceil(NE/256)
#define NSB 79                    // ceil(NN/256)
#define SMAX 224
#define HP (HD + 1)
#define SGRID 512                 // k_setup grid
#define SWAVES (SGRID * 4)

__device__ __forceinline__ float sigm(float x) {
  return 1.0f / (1.0f + expf(-x));
}

// --- setup: role-partitioned blocks + all blocks stride embed ---------------
__global__ __launch_bounds__(256) void k_setup(
    const float* __restrict__ node_feat, const int* __restrict__ node_type,
    const int* __restrict__ edge_type, const int* __restrict__ batch,
    const float* __restrict__ W_emb, const float* __restrict__ b_emb,
    const float* __restrict__ W_e1, const float* __restrict__ b_e1,
    const float* __restrict__ W_e2, const float* __restrict__ b_e2,
    const float* __restrict__ W_ih, const float* __restrict__ W_hh,
    float* __restrict__ h, float* __restrict__ Wty,
    float* __restrict__ W_ihT, float* __restrict__ W_hhT,
    int* __restrict__ bc, int* __restrict__ gstart) {
  __shared__ float emv[HD];
  __shared__ int wc[4][EDIM];
  int b = blockIdx.x, tid = threadIdx.x;
  int lane = tid & 63, wv = tid >> 6;

  if (b < 20) {
    // 5 edge-type matrices: Wty[t] = relu(W_e1[t]+b_e1) @ W_e2 + b_e2
    int t = b >> 2, chunk = b & 3;
    if (tid < HD) {
      float x = W_e1[t * HD + tid] + b_e1[tid];
      emv[tid] = x > 0.f ? x : 0.f;
    }
    __syncthreads();
    #pragma unroll
    for (int i = 0; i < 4; ++i) {
      int m = chunk * 1024 + i * 256 + tid;
      float acc = b_e2[m];
      #pragma unroll
      for (int j = 0; j < HD; ++j)
        acc = fmaf(emv[j], W_e2[j * 4096 + m], acc);
      Wty[t * 4096 + m] = acc;
    }
  } else if (b < 148) {
    // LSTM weight transpose
    int idx = (b - 20) * 256 + tid;                 // 0..32767
    { int g = idx >> 7, j = idx & 127; W_ihT[j * 256 + g] = W_ih[idx]; }
    if (idx < 4 * HD * HD) {
      int g = idx >> 6, j = idx & 63;
      W_hhT[j * 256 + g] = W_hh[idx];
    }
  } else if (b < 148 + NBLK) {
    // ballot per-block edge-type counts
    int e = (b - 148) * 256 + tid;
    int ty = (e < NE) ? edge_type[e] : -1;
    #pragma unroll
    for (int t = 0; t < EDIM; ++t) {
      unsigned long long m = __ballot(ty == t);
      if (lane == 0) wc[wv][t] = __popcll(m);
    }
    __syncthreads();
    if (tid < EDIM) {
      int s = 0;
      #pragma unroll
      for (int w = 0; w < 4; ++w) s += wc[w][tid];
      bc[(b - 148) * EDIM + tid] = s;
    }
  } else if (b < 148 + NBLK + NSB) {
    // CSR starts of sorted batch vector
    int n = (b - 148 - NBLK) * 256 + tid;
    if (n < NN) {
      int bb = batch[n];
      if (n == 0)
        for (int t = 0; t <= bb; ++t) gstart[t] = 0;
      int bn = (n + 1 < NN) ? batch[n + 1] : NB;
      for (int t = bb + 1; t <= bn; ++t) gstart[t] = n + 1;
    }
  }

  // embed (all blocks, grid-stride): h[n] = W_emb[type]+b + feat@W_emb[100:]
  int wid = __builtin_amdgcn_readfirstlane(b * 4 + wv);
  for (int n = wid; n < NN; n += SWAVES) {
    int t = __builtin_amdgcn_readfirstlane(node_type[n]);
    const float* row = node_feat + n * NFEAT;       // wave-uniform -> s_load
    float acc = b_emb[lane] + W_emb[t * HD + lane];
    #pragma unroll
    for (int f = 0; f < NFEAT; ++f)
      acc = fmaf(row[f], W_emb[(NTYPES + f) * HD + lane], acc);
    h[n * HD + lane] = acc;
  }
}

// --- place: per-block rescan of bc -> own base; block 0 writes offs ---------
__global__ __launch_bounds__(256) void k_place(
    const int* __restrict__ etype, const int* __restrict__ ei,
    const int* __restrict__ bc, int* __restrict__ offs,
    int* __restrict__ srcs, int* __restrict__ dsts) {
  __shared__ int buf[256];
  __shared__ int wcs[4][EDIM];
  __shared__ int basesh[EDIM];
  int b = blockIdx.x, tid = threadIdx.x;
  int lane = tid & 63, wv = tid >> 6;
  int running = 0;
  for (int t = 0; t < EDIM; ++t) {
    int v = (tid < NBLK) ? bc[tid * EDIM + t] : 0;
    buf[tid] = v;
    __syncthreads();
    #pragma unroll
    for (int off = 1; off < 256; off <<= 1) {
      int x = (tid >= off) ? buf[tid - off] : 0;
      __syncthreads();
      buf[tid] += x;
      __syncthreads();
    }
    if (tid == b) basesh[t] = running + buf[tid] - v;   // exclusive prefix @ b
    if (b == 0 && tid == 0) offs[t] = running;
    running += buf[255];
    __syncthreads();
  }
  if (b == 0 && tid == 0) offs[EDIM] = running;

  int e = b * 256 + tid;
  int ty = (e < NE) ? etype[e] : -1;
  int rank = 0;
  #pragma unroll
  for (int t = 0; t < EDIM; ++t) {
    unsigned long long m = __ballot(ty == t);
    if (lane == 0) wcs[wv][t] = __popcll(m);
    if (ty == t) rank = __popcll(m & ((1ull << lane) - 1ull));
  }
  __syncthreads();
  if (ty >= 0) {
    int base = basesh[ty];
    for (int w = 0; w < wv; ++w) base += wcs[w][ty];
    int pos = base + rank;
    srcs[pos] = ei[e];
    dsts[pos] = ei[NE + e];
  }
}

// --- root: hnext[n][o] = bias[o] + sum_k h[n][k]*root[k][o] (inits hnext) ---
__global__ __launch_bounds__(256) void k_root(
    const float* __restrict__ h, float* __restrict__ hnext,
    const float* __restrict__ root, const float* __restrict__ bias) {
  int lane = threadIdx.x & 63;
  int wid = __builtin_amdgcn_readfirstlane(blockIdx.x * 4 + (threadIdx.x >> 6));
  int nw = gridDim.x * 4;
  float w[HD];
  #pragma unroll
  for (int k = 0; k < HD; ++k) w[k] = root[k * HD + lane];
  float bb = bias[lane];
  for (int n = wid; n < NN; n += nw) {
    const float* row = h + n * HD;            // wave-uniform -> s_load
    float a0 = 0.f, a1 = 0.f, a2 = 0.f, a3 = 0.f;
    #pragma unroll
    for (int k = 0; k < HD; k += 4) {
      a0 = fmaf(row[k + 0], w[k + 0], a0);
      a1 = fmaf(row[k + 1], w[k + 1], a1);
      a2 = fmaf(row[k + 2], w[k + 2], a2);
      a3 = fmaf(row[k + 3], w[k + 3], a3);
    }
    hnext[n * HD + lane] = bb + ((a0 + a1) + (a2 + a3));
  }
}

// --- edge messages: hnext[dst] += h[src] @ W_{type}; wave per edge ----------
__global__ __launch_bounds__(256) void k_msg(
    const int* __restrict__ srcs, const int* __restrict__ dsts,
    const int* __restrict__ offs, const float* __restrict__ Wty,
    const float* __restrict__ h, float* __restrict__ hnext) {
  int lane = threadIdx.x & 63;
  int wid = __builtin_amdgcn_readfirstlane(blockIdx.x * 4 + (threadIdx.x >> 6));
  int nw = gridDim.x * 4;
  int per = (NE + nw - 1) / nw;
  int beg = wid * per;
  int end = beg + per; if (end > NE) end = NE;
  if (beg >= end) return;
  for (int t = 0; t < EDIM; ++t) {
    int lo = offs[t];     if (lo < beg) lo = beg;
    int hi = offs[t + 1]; if (hi > end) hi = end;
    if (lo >= hi) continue;
    float w[HD];
    #pragma unroll
    for (int k = 0; k < HD; ++k) w[k] = Wty[t * 4096 + k * HD + lane];
    for (int p = lo; p < hi; ++p) {
      int s = __builtin_amdgcn_readfirstlane(srcs[p]);
      int d = __builtin_amdgcn_readfirstlane(dsts[p]);
      const float* row = h + s * HD;          // wave-uniform -> s_load
      float a0 = 0.f, a1 = 0.f, a2 = 0.f, a3 = 0.f;
      #pragma unroll
      for (int k = 0; k < HD; k += 4) {
        a0 = fmaf(row[k + 0], w[k + 0], a0);
        a1 = fmaf(row[k + 1], w[k + 1], a1);
        a2 = fmaf(row[k + 2], w[k + 2], a2);
        a3 = fmaf(row[k + 3], w[k + 3], a3);
      }
      atomicAdd(&hnext[d * HD + lane], (a0 + a1) + (a2 + a3));
    }
  }
}

// --- Set2Set + output MLP, one block per graph ------------------------------
__global__ __launch_bounds__(256) void k_s2s(
    const float* __restrict__ h, const int* __restrict__ gstart,
    const float* __restrict__ W_ihT, const float* __restrict__ W_hhT,
    const float* __restrict__ b_ih, const float* __restrict__ b_hh,
    const float* __restrict__ W_o1, const float* __restrict__ b_o1,
    const float* __restrict__ W_o2, const float* __restrict__ b_o2,
    float* __restrict__ out) {
  __shared__ float hs[SMAX * HP];     // padded rows
  __shared__ float ebuf[SMAX];
  __shared__ float qstar[2 * HD];
  __shared__ float hxs[HD], cxs[HD], gates[4 * HD];
  __shared__ float redM[4], redS[4], redR[4][HD];
  __shared__ float hid[HD];
  int b = blockIdx.x;
  int tid = threadIdx.x;
  int lane = tid & 63, wv = tid >> 6;
  int st = gstart[b], en = gstart[b + 1];
  int cnt = en - st;
  int cached = cnt < SMAX ? cnt : SMAX;

  int total = cached * HD;
  for (int base = tid * 4; base < total; base += 1024) {
    float4 v = *reinterpret_cast<const float4*>(h + st * HD + base);
    int n = base >> 6, k = base & 63;
    float* row = hs + n * HP + k;
    row[0] = v.x; row[1] = v.y; row[2] = v.z; row[3] = v.w;
  }
  if (tid < 2 * HD) qstar[tid] = 0.f;
  if (tid < HD) { hxs[tid] = 0.f; cxs[tid] = 0.f; }
  __syncthreads();

  for (int it = 0; it < S2SIT; ++it) {
    float acc0 = b_ih[tid] + b_hh[tid], acc1 = 0.f;
    #pragma unroll 8
    for (int j = 0; j < 2 * HD; j += 2) {
      acc0 = fmaf(qstar[j],     W_ihT[j * 256 + tid],       acc0);
      acc1 = fmaf(qstar[j + 1], W_ihT[(j + 1) * 256 + tid], acc1);
    }
    #pragma unroll 8
    for (int j = 0; j < HD; j += 2) {
      acc0 = fmaf(hxs[j],     W_hhT[j * 256 + tid],       acc0);
      acc1 = fmaf(hxs[j + 1], W_hhT[(j + 1) * 256 + tid], acc1);
    }
    gates[tid] = acc0 + acc1;
    __syncthreads();
    if (tid < HD) {
      float ig = sigm(gates[tid]);
      float fg = sigm(gates[HD + tid]);
      float gg = tanhf(gates[2 * HD + tid]);
      float og = sigm(gates[3 * HD + tid]);
      float c = fmaf(fg, cxs[tid], ig * gg);
      cxs[tid] = c;
      hxs[tid] = og * tanhf(c);
    }
    __syncthreads();

    float e = -1e30f;
    if (tid < cached) {
      const float* row = hs + tid * HP;
      float d0 = 0.f, d1 = 0.f;
      #pragma unroll 8
      for (int k = 0; k < HD; k += 2) {
        d0 = fmaf(row[k],     hxs[k],     d0);
        d1 = fmaf(row[k + 1], hxs[k + 1], d1);
      }
      e = d0 + d1;
      ebuf[tid] = e;
    }
    float m = e;
    #pragma unroll
    for (int off = 32; off; off >>= 1) m = fmaxf(m, __shfl_xor(m, off, 64));
    float qreg = hxs[lane];
    for (int n = cached + wv; n < cnt; n += 4) {   // overflow tail
      float ev = h[(st + n) * HD + lane] * qreg;
      #pragma unroll
      for (int off = 32; off; off >>= 1) ev += __shfl_xor(ev, off, 64);
      m = fmaxf(m, ev);
    }
    if (lane == 0) redM[wv] = m;
    __syncthreads();
    float M = fmaxf(fmaxf(redM[0], redM[1]), fmaxf(redM[2], redM[3]));

    float sp = 0.f;
    if (tid < cached) {
      float a = expf(ebuf[tid] - M);
      ebuf[tid] = a;
      sp = a;
    }
    #pragma unroll
    for (int off = 32; off; off >>= 1) sp += __shfl_xor(sp, off, 64);
    __syncthreads();

    float r = 0.f;
    for (int n = wv; n < cached; n += 4)
      r = fmaf(ebuf[n], hs[n * HP + lane], r);
    float s_tail = 0.f;
    for (int n = cached + wv; n < cnt; n += 4) {   // overflow tail
      float v = h[(st + n) * HD + lane];
      float ev = v * qreg;
      #pragma unroll
      for (int off = 32; off; off >>= 1) ev += __shfl_xor(ev, off, 64);
      float a = expf(ev - M);
      s_tail += a;
      r = fmaf(a, v, r);
    }
    if (lane == 0) redS[wv] = sp + s_tail;
    redR[wv][lane] = r;
    __syncthreads();
    if (tid < HD) {
      float S = redS[0] + redS[1] + redS[2] + redS[3];
      float R = redR[0][tid] + redR[1][tid] + redR[2][tid] + redR[3][tid];
      if (S == 0.f) S = 1.f;            // empty-graph guard (matches ref)
      qstar[tid] = hxs[tid];
      qstar[HD + tid] = R / S;
    }
    __syncthreads();
  }

  if (tid < HD) {
    float acc = b_o1[tid];
    #pragma unroll 8
    for (int i = 0; i < 2 * HD; ++i)
      acc = fmaf(qstar[i], W_o1[i * HD + tid], acc);
    hid[tid] = acc > 0.f ? acc : 0.f;
  }
  __syncthreads();
  if (tid < HD) {
    float p = hid[tid] * W_o2[tid];
    #pragma unroll
    for (int off = 32; off; off >>= 1) p += __shfl_xor(p, off, 64);
    if (tid == 0) out[b] = p + b_o2[0];
  }
}

extern "C" void kernel_launch(void* const* d_in, const int* in_sizes, int n_in,
                              void* d_out, int out_size, void* d_ws, size_t ws_size,
                              hipStream_t stream) {
  const float* node_feat = (const float*)d_in[0];
  const int*   node_type = (const int*)d_in[1];
  const int*   edge_index= (const int*)d_in[2];
  const int*   edge_type = (const int*)d_in[3];
  const int*   batch     = (const int*)d_in[4];
  const float* W_emb     = (const float*)d_in[5];
  const float* b_emb     = (const float*)d_in[6];
  const float* W_e1      = (const float*)d_in[7];
  const float* b_e1      = (const float*)d_in[8];
  const float* W_e2      = (const float*)d_in[9];
  const float* b_e2      = (const float*)d_in[10];
  const float* roots     = (const float*)d_in[11];
  const float* conv_bias = (const float*)d_in[12];
  const float* W_ih      = (const float*)d_in[13];
  const float* W_hh      = (const float*)d_in[14];
  const float* b_ih      = (const float*)d_in[15];
  const float* b_hh      = (const float*)d_in[16];
  const float* W_o1      = (const float*)d_in[17];
  const float* b_o1      = (const float*)d_in[18];
  const float* W_o2      = (const float*)d_in[19];
  const float* b_o2      = (const float*)d_in[20];
  float* out = (float*)d_out;

  float* Wty    = (float*)d_ws;                 // 5*4096
  float* hA     = Wty + EDIM * 4096;            // NN*64
  float* hB     = hA + NN * HD;                 // NN*64
  float* W_ihT  = hB + NN * HD;                 // 128*256
  float* W_hhT  = W_ihT + 2 * HD * 4 * HD;      // 64*256
  int*   srcs   = (int*)(W_hhT + HD * 4 * HD);  // NE
  int*   dsts   = srcs + NE;                    // NE
  int*   bc     = dsts + NE;                    // NBLK*EDIM
  int*   offs   = bc + NBLK * EDIM;             // EDIM+1 (pad 8)
  int*   gstart = offs + 8;                     // NB+1

  k_setup<<<SGRID, 256, 0, stream>>>(node_feat, node_type, edge_type, batch,
                                     W_emb, b_emb, W_e1, b_e1, W_e2, b_e2,
                                     W_ih, W_hh, hA, Wty, W_ihT, W_hhT,
                                     bc, gstart);
  k_place<<<NBLK, 256, 0, stream>>>(edge_type, edge_index, bc, offs, srcs, dsts);

  const float* hcur = hA;
  float* hnxt = hB;
  for (int i = 0; i < 3; ++i) {
    k_root<<<512, 256, 0, stream>>>(hcur, hnxt, roots + i * HD * HD,
                                    conv_bias + i * HD);
    k_msg<<<2048, 256, 0, stream>>>(srcs, dsts, offs, Wty, hcur, hnxt);
    const float* tmp = hnxt; hnxt = (float*)hcur; hcur = tmp;
  }

  k_s2s<<<NB, 256, 0, stream>>>(hcur, gstart, W_ihT, W_hhT, b_ih, b_hh,
                                W_o1, b_o1, W_o2, b_o2, out);
}